// Round 4
// baseline (55947.937 us; speedup 1.0000x reference)
//
#include <hip/hip_runtime.h>
#include <hip/hip_bf16.h>
#include <cstdint>
#include <cstddef>

#define TSEQ 2048
#define BB   32
#define DD   256
#define UU   512
#define NCOL 1536
#define GB   32      // blocks per group
#define RING 8       // h1 ring depth (timesteps)

static __device__ __forceinline__ float aload(const float* p) {
    return __int_as_float(__hip_atomic_load((const int*)p, __ATOMIC_RELAXED,
                                            __HIP_MEMORY_SCOPE_AGENT));
}
static __device__ __forceinline__ void astore(float* p, float v) {
    __hip_atomic_store((int*)p, __float_as_int(v), __ATOMIC_RELAXED,
                       __HIP_MEMORY_SCOPE_AGENT);
}
static __device__ __forceinline__ unsigned f2bfu(float f) {
    __hip_bfloat16 b = __float2bfloat16(f);
    unsigned short s;
    __builtin_memcpy(&s, &b, 2);
    return (unsigned)s;
}
static __device__ __forceinline__ float bflo(unsigned u) { return __uint_as_float(u << 16); }
static __device__ __forceinline__ float bfhi(unsigned u) { return __uint_as_float(u & 0xffff0000u); }
static __device__ __forceinline__ int swz512(int k) { return k ^ (((k >> 6) & 7) << 2); }
static __device__ __forceinline__ int swz256(int k) { return k ^ (((k >> 5) & 7) << 2); }

// ---------------------------------------------------------------------------
// One persistent kernel, 512 blocks x 512 threads (16 waves/CU exactly).
//  blocks 0..255  = role A: layer-1 scan, xp1 computed in-block from x,k1.
//  blocks 256..511= role C: layer-2 scan, xp2 computed in-block from h1,k2.
// h1 published through an 8-deep ring at the coherence point (relaxed AGENT
// atomics only — NO fences anywhere). A is throttled by C's flags (>= t-7)
// so ring slots are never overwritten before consumption. Acyclic dep order:
// A@t <- {A-group@t-1, C-group@t-8};  C@t <- {C-group@t-1, A-group@t}.
// ---------------------------------------------------------------------------
__global__ __launch_bounds__(512, 4)
void gru_fused(const float* __restrict__ x,   const float* __restrict__ h0,
               const float* __restrict__ k1,  const float* __restrict__ rk1,
               const float* __restrict__ b1,  const float* __restrict__ k2,
               const float* __restrict__ rk2, const float* __restrict__ b2,
               float* h1ring,                 // [RING][BB][UU]
               float* hp2,                    // [2][BB][UU]
               int* aflags, int* cflags,      // [256] each, zeroed
               float* __restrict__ out2, float* __restrict__ state1,
               float* __restrict__ state2)
{
    __shared__ float hl1[4][512];
    __shared__ float hl2[4][512];
    __shared__ float xls[2][4][256];
    __shared__ float innR[48][4];
    __shared__ float innX[48][4];

    const int tid  = threadIdx.x;
    const int bid  = blockIdx.x;
    const bool isA = (bid < 256);
    const int lb   = isA ? bid : (bid - 256);
    const int g    = lb & 7,  slot = lb >> 3;
    const int u0   = slot * 16, b0 = g * 4;
    const int c    = tid >> 3, j = tid & 7;
    const int jsw  = j << 2;
    const int col  = (c < 48) ? ((c >> 4) * UU + u0 + (c & 15)) : 0;

    if (isA) {
        // ================= ROLE A : layer-1 =================
        float    wr[64];     // rk1 column slice, f32 (recurrence: keep exact)
        unsigned wk[16];     // k1 column slice, bf16-packed
        if (c < 48) {
            const float* rb = rk1 + (size_t)(j * 64) * NCOL + col;
            #pragma unroll
            for (int q = 0; q < 64; ++q) wr[q] = rb[(size_t)q * NCOL];
            const float* kb = k1 + (size_t)(j * 32) * NCOL + col;
            #pragma unroll
            for (int m = 0; m < 16; ++m)
                wk[m] = f2bfu(kb[(size_t)(2 * m) * NCOL])
                      | (f2bfu(kb[(size_t)(2 * m + 1) * NCOL]) << 16);
        }
        float binz = 0, binr = 0, binh = 0, brz = 0, brr = 0, brh = 0;
        if (tid < 64) {
            int iu = tid & 15;
            binz = b1[u0 + iu]; binr = b1[UU + u0 + iu]; binh = b1[2 * UU + u0 + iu];
            brz = b1[NCOL + u0 + iu]; brr = b1[NCOL + UU + u0 + iu];
            brh = b1[NCOL + 2 * UU + u0 + iu];
        }
        #pragma unroll
        for (int m = 0; m < 2; ++m) {           // prefill x[:,0,:]
            int idx = m * 512 + tid;
            int row = idx >> 8, k = idx & 255;
            xls[0][row][swz256(k)] = x[((size_t)(b0 + row) * TSEQ + 0) * DD + k];
        }
        __syncthreads();

        for (int t = 0; t < TSEQ; ++t) {
            if (t > 0) {
                if (tid < 64) {
                    const int* fp = (tid < 32) ? &aflags[g * GB + tid]
                                               : &cflags[g * GB + (tid - 32)];
                    const int thr = (tid < 32) ? t : (t - (RING - 1));
                    while (!__all(__hip_atomic_load(fp, __ATOMIC_RELAXED,
                                  __HIP_MEMORY_SCOPE_AGENT) >= thr)) {}
                }
                __syncthreads();
            }
            {   // stage h1[t-1]
                const float* hs = h1ring + (size_t)((t - 1) & 7) * BB * UU;
                #pragma unroll
                for (int i = 0; i < 4; ++i) {
                    int idx = i * 512 + tid;
                    int row = idx >> 9, k = idx & 511;
                    float v = (t == 0) ? h0[(size_t)(b0 + row) * UU + k]
                                       : aload(&hs[(size_t)(b0 + row) * UU + k]);
                    hl1[row][swz512(k)] = v;
                }
            }
            __syncthreads();

            const int cur = t & 1;
            if (c < 48) {
                float aR0=0,aR1=0,aR2=0,aR3=0,aX0=0,aX1=0,aX2=0,aX3=0;
                const int kb = j * 64;
                #pragma unroll
                for (int q0 = 0; q0 < 64; q0 += 4) {
                    int p = kb + (q0 ^ jsw);
                    float4 v0 = *(const float4*)&hl1[0][p];
                    float4 v1 = *(const float4*)&hl1[1][p];
                    float4 v2 = *(const float4*)&hl1[2][p];
                    float4 v3 = *(const float4*)&hl1[3][p];
                    aR0 = fmaf(wr[q0+0], v0.x, aR0); aR1 = fmaf(wr[q0+0], v1.x, aR1);
                    aR2 = fmaf(wr[q0+0], v2.x, aR2); aR3 = fmaf(wr[q0+0], v3.x, aR3);
                    aR0 = fmaf(wr[q0+1], v0.y, aR0); aR1 = fmaf(wr[q0+1], v1.y, aR1);
                    aR2 = fmaf(wr[q0+1], v2.y, aR2); aR3 = fmaf(wr[q0+1], v3.y, aR3);
                    aR0 = fmaf(wr[q0+2], v0.z, aR0); aR1 = fmaf(wr[q0+2], v1.z, aR1);
                    aR2 = fmaf(wr[q0+2], v2.z, aR2); aR3 = fmaf(wr[q0+2], v3.z, aR3);
                    aR0 = fmaf(wr[q0+3], v0.w, aR0); aR1 = fmaf(wr[q0+3], v1.w, aR1);
                    aR2 = fmaf(wr[q0+3], v2.w, aR2); aR3 = fmaf(wr[q0+3], v3.w, aR3);
                }
                const int kb2 = j * 32;
                #pragma unroll
                for (int q0 = 0; q0 < 32; q0 += 4) {
                    int p = kb2 + (q0 ^ jsw);
                    float4 v0 = *(const float4*)&xls[cur][0][p];
                    float4 v1 = *(const float4*)&xls[cur][1][p];
                    float4 v2 = *(const float4*)&xls[cur][2][p];
                    float4 v3 = *(const float4*)&xls[cur][3][p];
                    unsigned wa = wk[q0 >> 1], wb = wk[(q0 >> 1) + 1];
                    float w0 = bflo(wa), w1 = bfhi(wa), w2 = bflo(wb), w3 = bfhi(wb);
                    aX0 = fmaf(w0, v0.x, aX0); aX1 = fmaf(w0, v1.x, aX1);
                    aX2 = fmaf(w0, v2.x, aX2); aX3 = fmaf(w0, v3.x, aX3);
                    aX0 = fmaf(w1, v0.y, aX0); aX1 = fmaf(w1, v1.y, aX1);
                    aX2 = fmaf(w1, v2.y, aX2); aX3 = fmaf(w1, v3.y, aX3);
                    aX0 = fmaf(w2, v0.z, aX0); aX1 = fmaf(w2, v1.z, aX1);
                    aX2 = fmaf(w2, v2.z, aX2); aX3 = fmaf(w2, v3.z, aX3);
                    aX0 = fmaf(w3, v0.w, aX0); aX1 = fmaf(w3, v1.w, aX1);
                    aX2 = fmaf(w3, v2.w, aX2); aX3 = fmaf(w3, v3.w, aX3);
                }
                #pragma unroll
                for (int m = 1; m < 8; m <<= 1) {
                    aR0 += __shfl_xor(aR0, m); aR1 += __shfl_xor(aR1, m);
                    aR2 += __shfl_xor(aR2, m); aR3 += __shfl_xor(aR3, m);
                    aX0 += __shfl_xor(aX0, m); aX1 += __shfl_xor(aX1, m);
                    aX2 += __shfl_xor(aX2, m); aX3 += __shfl_xor(aX3, m);
                }
                if (j == 0) {
                    innR[c][0]=aR0; innR[c][1]=aR1; innR[c][2]=aR2; innR[c][3]=aR3;
                    innX[c][0]=aX0; innX[c][1]=aX1; innX[c][2]=aX2; innX[c][3]=aX3;
                }
            } else if (t + 1 < TSEQ) {          // tid>=384: prefetch x[t+1]
                int p = tid - 384, nb = (t + 1) & 1;
                #pragma unroll
                for (int m = 0; m < 8; ++m) {
                    int idx = m * 128 + p;
                    int row = idx >> 8, k = idx & 255;
                    xls[nb][row][swz256(k)] =
                        x[((size_t)(b0 + row) * TSEQ + (t + 1)) * DD + k];
                }
            }
            __syncthreads();

            if (tid < 64) {
                int bl = tid >> 4, iu = tid & 15, ug = u0 + iu;
                float rz = innR[iu][bl]      + brz;
                float rr = innR[16 + iu][bl] + brr;
                float rh = innR[32 + iu][bl] + brh;
                float xz = innX[iu][bl]      + binz;
                float xr = innX[16 + iu][bl] + binr;
                float xh = innX[32 + iu][bl] + binh;
                float z  = 1.f / (1.f + expf(-(xz + rz)));
                float r  = 1.f / (1.f + expf(-(xr + rr)));
                float hh = tanhf(xh + r * rh);
                float hold = hl1[bl][swz512(ug)];
                float hnew = z * hold + (1.f - z) * hh;
                astore(h1ring + (size_t)(t & 7) * BB * UU
                              + (size_t)(b0 + bl) * UU + ug, hnew);
                if (t == TSEQ - 1) state1[(size_t)(b0 + bl) * UU + ug] = hnew;
            }
            __syncthreads();   // drains vmcnt: h stores at MALL before flag
            if (tid == 0)
                __hip_atomic_store(&aflags[g * GB + slot], t + 1,
                                   __ATOMIC_RELAXED, __HIP_MEMORY_SCOPE_AGENT);
        }
    } else {
        // ================= ROLE C : layer-2 =================
        unsigned wr2[32];    // rk2 bf16-packed
        unsigned wk2[32];    // k2  bf16-packed
        if (c < 48) {
            const float* rb = rk2 + (size_t)(j * 64) * NCOL + col;
            const float* kb = k2  + (size_t)(j * 64) * NCOL + col;
            #pragma unroll
            for (int m = 0; m < 32; ++m) {
                wr2[m] = f2bfu(rb[(size_t)(2 * m) * NCOL])
                       | (f2bfu(rb[(size_t)(2 * m + 1) * NCOL]) << 16);
                wk2[m] = f2bfu(kb[(size_t)(2 * m) * NCOL])
                       | (f2bfu(kb[(size_t)(2 * m + 1) * NCOL]) << 16);
            }
        }
        float binz = 0, binr = 0, binh = 0, brz = 0, brr = 0, brh = 0;
        if (tid < 64) {
            int iu = tid & 15;
            binz = b2[u0 + iu]; binr = b2[UU + u0 + iu]; binh = b2[2 * UU + u0 + iu];
            brz = b2[NCOL + u0 + iu]; brr = b2[NCOL + UU + u0 + iu];
            brh = b2[NCOL + 2 * UU + u0 + iu];
        }
        __syncthreads();

        for (int t = 0; t < TSEQ; ++t) {
            if (tid < 64) {
                const int* fp = (tid < 32) ? &cflags[g * GB + tid]
                                           : &aflags[g * GB + (tid - 32)];
                const int thr = (tid < 32) ? t : (t + 1);
                while (!__all(__hip_atomic_load(fp, __ATOMIC_RELAXED,
                              __HIP_MEMORY_SCOPE_AGENT) >= thr)) {}
            }
            __syncthreads();
            {   // stage h1[t] (ring) and h2[t-1] (pingpong)
                const float* hs1 = h1ring + (size_t)(t & 7) * BB * UU;
                const float* hs2 = hp2 + (size_t)((t + 1) & 1) * BB * UU;
                #pragma unroll
                for (int i = 0; i < 4; ++i) {
                    int idx = i * 512 + tid;
                    int row = idx >> 9, k = idx & 511;
                    hl1[row][swz512(k)] = aload(&hs1[(size_t)(b0 + row) * UU + k]);
                    float v = (t == 0) ? h0[(size_t)(b0 + row) * UU + k]
                                       : aload(&hs2[(size_t)(b0 + row) * UU + k]);
                    hl2[row][swz512(k)] = v;
                }
            }
            __syncthreads();

            if (c < 48) {
                float aR0=0,aR1=0,aR2=0,aR3=0,aX0=0,aX1=0,aX2=0,aX3=0;
                const int kb = j * 64;
                #pragma unroll
                for (int q0 = 0; q0 < 64; q0 += 4) {
                    int p = kb + (q0 ^ jsw);
                    float4 v0 = *(const float4*)&hl2[0][p];
                    float4 v1 = *(const float4*)&hl2[1][p];
                    float4 v2 = *(const float4*)&hl2[2][p];
                    float4 v3 = *(const float4*)&hl2[3][p];
                    unsigned wa = wr2[q0 >> 1], wb = wr2[(q0 >> 1) + 1];
                    float w0 = bflo(wa), w1 = bfhi(wa), w2 = bflo(wb), w3 = bfhi(wb);
                    aR0 = fmaf(w0, v0.x, aR0); aR1 = fmaf(w0, v1.x, aR1);
                    aR2 = fmaf(w0, v2.x, aR2); aR3 = fmaf(w0, v3.x, aR3);
                    aR0 = fmaf(w1, v0.y, aR0); aR1 = fmaf(w1, v1.y, aR1);
                    aR2 = fmaf(w1, v2.y, aR2); aR3 = fmaf(w1, v3.y, aR3);
                    aR0 = fmaf(w2, v0.z, aR0); aR1 = fmaf(w2, v1.z, aR1);
                    aR2 = fmaf(w2, v2.z, aR2); aR3 = fmaf(w2, v3.z, aR3);
                    aR0 = fmaf(w3, v0.w, aR0); aR1 = fmaf(w3, v1.w, aR1);
                    aR2 = fmaf(w3, v2.w, aR2); aR3 = fmaf(w3, v3.w, aR3);
                    float4 u0v = *(const float4*)&hl1[0][p];
                    float4 u1v = *(const float4*)&hl1[1][p];
                    float4 u2v = *(const float4*)&hl1[2][p];
                    float4 u3v = *(const float4*)&hl1[3][p];
                    unsigned xa = wk2[q0 >> 1], xb = wk2[(q0 >> 1) + 1];
                    float y0 = bflo(xa), y1 = bfhi(xa), y2 = bflo(xb), y3 = bfhi(xb);
                    aX0 = fmaf(y0, u0v.x, aX0); aX1 = fmaf(y0, u1v.x, aX1);
                    aX2 = fmaf(y0, u2v.x, aX2); aX3 = fmaf(y0, u3v.x, aX3);
                    aX0 = fmaf(y1, u0v.y, aX0); aX1 = fmaf(y1, u1v.y, aX1);
                    aX2 = fmaf(y1, u2v.y, aX2); aX3 = fmaf(y1, u3v.y, aX3);
                    aX0 = fmaf(y2, u0v.z, aX0); aX1 = fmaf(y2, u1v.z, aX1);
                    aX2 = fmaf(y2, u2v.z, aX2); aX3 = fmaf(y2, u3v.z, aX3);
                    aX0 = fmaf(y3, u0v.w, aX0); aX1 = fmaf(y3, u1v.w, aX1);
                    aX2 = fmaf(y3, u2v.w, aX2); aX3 = fmaf(y3, u3v.w, aX3);
                }
                #pragma unroll
                for (int m = 1; m < 8; m <<= 1) {
                    aR0 += __shfl_xor(aR0, m); aR1 += __shfl_xor(aR1, m);
                    aR2 += __shfl_xor(aR2, m); aR3 += __shfl_xor(aR3, m);
                    aX0 += __shfl_xor(aX0, m); aX1 += __shfl_xor(aX1, m);
                    aX2 += __shfl_xor(aX2, m); aX3 += __shfl_xor(aX3, m);
                }
                if (j == 0) {
                    innR[c][0]=aR0; innR[c][1]=aR1; innR[c][2]=aR2; innR[c][3]=aR3;
                    innX[c][0]=aX0; innX[c][1]=aX1; innX[c][2]=aX2; innX[c][3]=aX3;
                }
            }
            __syncthreads();

            if (tid < 64) {
                int bl = tid >> 4, iu = tid & 15, ug = u0 + iu;
                float rz = innR[iu][bl]      + brz;
                float rr = innR[16 + iu][bl] + brr;
                float rh = innR[32 + iu][bl] + brh;
                float xz = innX[iu][bl]      + binz;
                float xr = innX[16 + iu][bl] + binr;
                float xh = innX[32 + iu][bl] + binh;
                float z  = 1.f / (1.f + expf(-(xz + rz)));
                float r  = 1.f / (1.f + expf(-(xr + rr)));
                float hh = tanhf(xh + r * rh);
                float hold = hl2[bl][swz512(ug)];
                float hnew = z * hold + (1.f - z) * hh;
                astore(hp2 + (size_t)(t & 1) * BB * UU
                           + (size_t)(b0 + bl) * UU + ug, hnew);
                out2[((size_t)(b0 + bl) * TSEQ + t) * UU + ug] = hnew;
                if (t == TSEQ - 1) state2[(size_t)(b0 + bl) * UU + ug] = hnew;
            }
            __syncthreads();
            if (tid == 0)
                __hip_atomic_store(&cflags[g * GB + slot], t + 1,
                                   __ATOMIC_RELAXED, __HIP_MEMORY_SCOPE_AGENT);
        }
    }
}

// ---------------------------------------------------------------------------
extern "C" void kernel_launch(void* const* d_in, const int* in_sizes, int n_in,
                              void* d_out, int out_size, void* d_ws, size_t ws_size,
                              hipStream_t stream)
{
    const float* x      = (const float*)d_in[0];
    const float* hidden = (const float*)d_in[1];
    const float* k1     = (const float*)d_in[2];
    const float* rk1    = (const float*)d_in[3];
    const float* b1     = (const float*)d_in[4];
    const float* k2     = (const float*)d_in[5];
    const float* rk2    = (const float*)d_in[6];
    const float* b2     = (const float*)d_in[7];

    float* h1ring = (float*)d_ws;                         // RING*BB*UU
    float* hp2    = h1ring + (size_t)RING * BB * UU;      // 2*BB*UU
    int*   aflags = (int*)(hp2 + 2 * (size_t)BB * UU);
    int*   cflags = aflags + 256;

    size_t need = ((size_t)(RING + 2) * BB * UU) * sizeof(float) + 512 * sizeof(int);
    if (ws_size < need) return;

    float* out2   = (float*)d_out;
    float* state1 = out2 + (size_t)BB * TSEQ * UU;
    float* state2 = state1 + BB * UU;

    hipMemsetAsync(aflags, 0, 512 * sizeof(int), stream);

    gru_fused<<<512, 512, 0, stream>>>(x, hidden, k1, rk1, b1, k2, rk2, b2,
                                       h1ring, hp2, aflags, cflags,
                                       out2, state1, state2);
}